// Round 1
// baseline (1327.515 us; speedup 1.0000x reference)
//
#include <hip/hip_runtime.h>

typedef unsigned short u16t;
typedef unsigned int   u32t;
typedef __attribute__((ext_vector_type(8))) __bf16          bf16x8;
typedef __attribute__((ext_vector_type(8))) unsigned short  u16x8;
typedef __attribute__((ext_vector_type(4))) unsigned short  u16x4;
typedef __attribute__((ext_vector_type(4))) float           floatx4;

// f32 -> bf16 round-to-nearest-even (no NaN inputs in this problem)
__device__ __forceinline__ u16t f2b(float f){
  u32t u = __builtin_bit_cast(u32t, f);
  u += 0x7fffu + ((u >> 16) & 1u);
  return (u16t)(u >> 16);
}
__device__ __forceinline__ float b2f(u16t h){
  return __builtin_bit_cast(float, (u32t)h << 16);
}
// async global->LDS, 16B per lane. lds ptr must be wave-uniform (HW adds lane*16).
__device__ __forceinline__ void async16(const void* g, void* l){
  __builtin_amdgcn_global_load_lds((__attribute__((address_space(1))) void*)g,
                                   (__attribute__((address_space(3))) void*)l, 16, 0, 0);
}
__device__ __forceinline__ bf16x8 ldfrag(const u16t* p){
  return __builtin_bit_cast(bf16x8, *(const u16x8*)p);
}

// ---------------------------------------------------------------- cvt f32->bf16
__global__ __launch_bounds__(256)
void cvt_f32_bf16(const float* __restrict__ in, u16t* __restrict__ out, int n4){
  typedef __attribute__((ext_vector_type(4))) float f32x4;
  const f32x4* in4 = (const f32x4*)in;
  int stride = gridDim.x * blockDim.x;
  for (int i = blockIdx.x * blockDim.x + threadIdx.x; i < n4; i += stride){
    f32x4 v = in4[i];
    u16x4 o; o[0]=f2b(v[0]); o[1]=f2b(v[1]); o[2]=f2b(v[2]); o[3]=f2b(v[3]);
    *(u16x4*)(out + (size_t)i * 4) = o;
  }
}

// ---------------------------------------------------------------- GEMM C = A * B^T
// A: (M,K) bf16 row-major, B: (N,K) bf16 row-major, C: (M,N) f32 or bf16.
// m97 structure: 128x128 tile, BK=32, 4 waves, 4x4 16x16x32 MFMA per wave,
// global_load_lds width=16 staging, 2 barriers per K-step.
template<int OUT_BF16>
__global__ __launch_bounds__(256)
void gemm_bt(const u16t* __restrict__ A, const u16t* __restrict__ B,
             void* __restrict__ Cv, int M, int N, int K)
{
  __shared__ u16t sA[128 * 32];
  __shared__ u16t sB[128 * 32];
  const int tid  = threadIdx.x;
  const int wave = tid >> 6, lane = tid & 63;
  const int lrow = lane & 15, quad = lane >> 4;
  const int m0 = blockIdx.y * 128, n0 = blockIdx.x * 128;
  const int wm = (wave >> 1) * 64, wn = (wave & 1) * 64;

  floatx4 acc[4][4] = {};

  // staging geometry: tile is 128 rows x 32 cols bf16 (64B/row, 8KB total)
  // round r: byte = r*4096 + wave*1024 + lane*16 ; row = byte>>6 ; kbyte = byte&63
  const int byte0 = wave * 1024 + lane * 16;
  const int row0  = byte0 >> 6;
  const int kel0  = (byte0 & 63) >> 1;
  const int row1  = row0 + 64;

  char* lA0 = (char*)sA + wave * 1024;
  char* lA1 = (char*)sA + 4096 + wave * 1024;
  char* lB0 = (char*)sB + wave * 1024;
  char* lB1 = (char*)sB + 4096 + wave * 1024;

  const u16t* gA0 = A + (size_t)(m0 + row0) * K + kel0;
  const u16t* gA1 = A + (size_t)(m0 + row1) * K + kel0;
  const u16t* gB0 = B + (size_t)(n0 + row0) * K + kel0;
  const u16t* gB1 = B + (size_t)(n0 + row1) * K + kel0;

  for (int k0 = 0; k0 < K; k0 += 32){
    async16(gA0 + k0, lA0);
    async16(gA1 + k0, lA1);
    async16(gB0 + k0, lB0);
    async16(gB1 + k0, lB1);
    __syncthreads();   // drains vmcnt -> LDS tiles ready
    bf16x8 a[4], b[4];
#pragma unroll
    for (int i = 0; i < 4; ++i) a[i] = ldfrag(&sA[(wm + i * 16 + lrow) * 32 + quad * 8]);
#pragma unroll
    for (int j = 0; j < 4; ++j) b[j] = ldfrag(&sB[(wn + j * 16 + lrow) * 32 + quad * 8]);
#pragma unroll
    for (int i = 0; i < 4; ++i)
#pragma unroll
      for (int j = 0; j < 4; ++j)
        acc[i][j] = __builtin_amdgcn_mfma_f32_16x16x32_bf16(a[i], b[j], acc[i][j], 0, 0, 0);
    __syncthreads();   // protect LDS from next-iter staging
  }

  // epilogue: C/D layout col=lane&15, row=quad*4+reg (m89-verified)
#pragma unroll
  for (int i = 0; i < 4; ++i)
#pragma unroll
    for (int j = 0; j < 4; ++j)
#pragma unroll
      for (int r = 0; r < 4; ++r){
        int row = m0 + wm + i * 16 + quad * 4 + r;
        int col = n0 + wn + j * 16 + lrow;
        float v = acc[i][j][r];
        if (OUT_BF16) ((u16t*)Cv)[(size_t)row * N + col] = f2b(v);
        else          ((float*)Cv)[(size_t)row * N + col] = v;
      }
}

// ---------------------------------------------------------------- RoPE + layout
// qkvb: (B*T, 6144) bf16. Writes qr (B,32,T,128), kr (B,8,T,128), rotary applied.
__global__ __launch_bounds__(256)
void rope_qk(const u16t* __restrict__ qkvb, const float* __restrict__ cosp,
             const float* __restrict__ sinp, u16t* __restrict__ qr, u16t* __restrict__ kr)
{
  const int row = blockIdx.x;            // b*2048 + t
  const int b = row >> 11, t = row & 2047;
  const u16t* src = qkvb + (size_t)row * 6144;
  for (int p = threadIdx.x; p < 2560; p += 256){
    u32t both = *(const u32t*)(src + 2 * p);
    float t0 = b2f((u16t)(both & 0xffff));
    float t1 = b2f((u16t)(both >> 16));
    int j = p & 63;
    float c = cosp[t * 64 + j], s = sinp[t * 64 + j];
    float o0 = t0 * c - t1 * s;
    float o1 = t0 * s + t1 * c;
    u32t packed = (u32t)f2b(o0) | ((u32t)f2b(o1) << 16);
    if (p < 2048){
      int h = p >> 6;
      *(u32t*)(qr + (((size_t)(b * 32 + h) * 2048 + t) * 128 + 2 * j)) = packed;
    } else {
      int kh = (p - 2048) >> 6;
      *(u32t*)(kr + (((size_t)(b * 8 + kh) * 2048 + t) * 128 + 2 * j)) = packed;
    }
  }
}

// ---------------------------------------------------------------- V transpose
// qkvb v-region -> vt (B,8,128,T) bf16 (d-major, t contiguous) via LDS tile transpose
__global__ __launch_bounds__(256)
void vtrans(const u16t* __restrict__ qkvb, u16t* __restrict__ vt)
{
  __shared__ u16t sV[64 * 128];
  const int tid = threadIdx.x;
  const int blk = blockIdx.x;                 // (b, kvh, tile)
  const int tile = blk & 31, kvh = (blk >> 5) & 7, b = blk >> 8;
  const int t0 = tile * 64;
  const size_t srcbase = (size_t)(b * 2048 + t0) * 6144 + 5120 + kvh * 128;
#pragma unroll
  for (int it = 0; it < 4; ++it){
    int task = it * 256 + tid;
    int rrow = task >> 4, cb = task & 15;
    *(u16x8*)&sV[rrow * 128 + cb * 8] =
        *(const u16x8*)(qkvb + srcbase + (size_t)rrow * 6144 + cb * 8);
  }
  __syncthreads();
  const size_t dstbase = (size_t)((b * 8 + kvh) * 128) * 2048 + t0;
#pragma unroll
  for (int it = 0; it < 4; ++it){
    int task = it * 256 + tid;
    int tc = task & 7, d = task >> 3;
    u16x8 v;
#pragma unroll
    for (int j = 0; j < 8; ++j) v[j] = sV[(tc * 8 + j) * 128 + d];
    *(u16x8*)(vt + dstbase + (size_t)d * 2048 + tc * 8) = v;
  }
}

// ---------------------------------------------------------------- flash attention
// Q (B,32,T,128), K (B,8,T,128), Vt (B,8,128,T) bf16 -> Y (B,T,32*128) bf16.
// 64-row Q tile per block, 64-col KV tiles, online softmax (exp2-domain), causal.
__global__ __launch_bounds__(256)
void attn_fwd(const u16t* __restrict__ Qg, const u16t* __restrict__ Kg,
              const u16t* __restrict__ Vt, u16t* __restrict__ Y)
{
  __shared__ u16t sQ[64 * 128];   // [q][d]
  __shared__ u16t sK[64 * 128];   // [kv][d]
  __shared__ u16t sV[128 * 64];   // [d][kv]  (from Vt)
  __shared__ u16t sP[64 * 72];    // [q][kv], stride 72 (144B rows: 16B-aligned, bank-spread)
  const int tid  = threadIdx.x;
  const int wave = tid >> 6, lane = tid & 63;
  const int lrow = lane & 15, quad = lane >> 4;
  const int q0 = blockIdx.x * 64;
  const int bh = blockIdx.y;
  const int b = bh >> 5, h = bh & 31, kvh = h >> 2;
  const float qscale = 0.088388347648318447f * 1.4426950408889634f; // 1/sqrt(128)*log2(e)

  // stage Q tile (16KB, contiguous in (B,H,T,D))
  const size_t qbase = ((size_t)bh * 2048 + q0) * 128;
#pragma unroll
  for (int r = 0; r < 4; ++r){
    int byte = r * 4096 + wave * 1024 + lane * 16;
    async16(Qg + qbase + (byte >> 1), (char*)sQ + r * 4096 + wave * 1024);
  }

  float mi[4] = {-1e30f, -1e30f, -1e30f, -1e30f};
  float li[4] = {0.f, 0.f, 0.f, 0.f};
  floatx4 o[8] = {};
  const size_t kbase = ((size_t)(b * 8 + kvh) * 2048) * 128;
  const size_t vbase = ((size_t)(b * 8 + kvh) * 128) * 2048;
  const int qrow_base = q0 + wave * 16 + quad * 4;
  const int ktiles = (q0 >> 6) + 1;

  for (int kt = 0; kt < ktiles; ++kt){
    const int k0 = kt * 64;
#pragma unroll
    for (int r = 0; r < 4; ++r){
      int byte = r * 4096 + wave * 1024 + lane * 16;
      async16(Kg + kbase + (size_t)k0 * 128 + (byte >> 1),
              (char*)sK + r * 4096 + wave * 1024);
    }
#pragma unroll
    for (int r = 0; r < 4; ++r){
      int byte = r * 4096 + wave * 1024 + lane * 16;   // d = byte>>7, koff = (byte&127)>>1
      async16(Vt + vbase + (size_t)(byte >> 7) * 2048 + k0 + ((byte & 127) >> 1),
              (char*)sV + r * 4096 + wave * 1024);
    }
    __syncthreads();

    // S = Q K^T : wave owns q-rows [16*wave, 16*wave+16); 4 n-tiles over 64 kv
    floatx4 s[4] = {};
#pragma unroll
    for (int kk = 0; kk < 4; ++kk){
      bf16x8 aq = ldfrag(&sQ[(wave * 16 + lrow) * 128 + kk * 32 + quad * 8]);
#pragma unroll
      for (int nt = 0; nt < 4; ++nt){
        bf16x8 bk = ldfrag(&sK[(nt * 16 + lrow) * 128 + kk * 32 + quad * 8]);
        s[nt] = __builtin_amdgcn_mfma_f32_16x16x32_bf16(aq, bk, s[nt], 0, 0, 0);
      }
    }

    // scale (+ causal mask on the diagonal tile)
    float tt[4][4];
#pragma unroll
    for (int nt = 0; nt < 4; ++nt)
#pragma unroll
      for (int r = 0; r < 4; ++r)
        tt[nt][r] = s[nt][r] * qscale;
    if (kt == ktiles - 1){        // k0 == q0 : partial mask
#pragma unroll
      for (int nt = 0; nt < 4; ++nt){
        int kc = k0 + nt * 16 + lrow;
#pragma unroll
        for (int r = 0; r < 4; ++r)
          if (kc > qrow_base + r) tt[nt][r] = -1e30f;
      }
    }

    // row max over 64 cols: 4 in-thread + 16-lane butterfly (rows live in quad groups)
    float rmax[4];
#pragma unroll
    for (int r = 0; r < 4; ++r)
      rmax[r] = fmaxf(fmaxf(tt[0][r], tt[1][r]), fmaxf(tt[2][r], tt[3][r]));
#pragma unroll
    for (int off = 1; off < 16; off <<= 1){
#pragma unroll
      for (int r = 0; r < 4; ++r)
        rmax[r] = fmaxf(rmax[r], __shfl_xor(rmax[r], off, 64));
    }
    float alpha[4];
#pragma unroll
    for (int r = 0; r < 4; ++r){
      float mn = fmaxf(mi[r], rmax[r]);
      alpha[r] = exp2f(mi[r] - mn);
      mi[r] = mn;
    }
    // P = exp2(tt - m), write to LDS (C-layout -> natural [q][kv])
    float lsum[4] = {0.f, 0.f, 0.f, 0.f};
#pragma unroll
    for (int nt = 0; nt < 4; ++nt)
#pragma unroll
      for (int r = 0; r < 4; ++r){
        float e = exp2f(tt[nt][r] - mi[r]);
        lsum[r] += e;
        sP[(wave * 16 + quad * 4 + r) * 72 + nt * 16 + lrow] = f2b(e);
      }
#pragma unroll
    for (int off = 1; off < 16; off <<= 1){
#pragma unroll
      for (int r = 0; r < 4; ++r)
        lsum[r] += __shfl_xor(lsum[r], off, 64);
    }
#pragma unroll
    for (int r = 0; r < 4; ++r) li[r] = li[r] * alpha[r] + lsum[r];
#pragma unroll
    for (int nt = 0; nt < 8; ++nt){
      o[nt][0] *= alpha[0]; o[nt][1] *= alpha[1];
      o[nt][2] *= alpha[2]; o[nt][3] *= alpha[3];
    }
    __syncthreads();   // sP visible

    // O += P V : A from sP (A-layout), B from sV (V^T natural)
#pragma unroll
    for (int kk = 0; kk < 2; ++kk){
      bf16x8 ap = ldfrag(&sP[(wave * 16 + lrow) * 72 + kk * 32 + quad * 8]);
#pragma unroll
      for (int nt = 0; nt < 8; ++nt){
        bf16x8 bv = ldfrag(&sV[(nt * 16 + lrow) * 64 + kk * 32 + quad * 8]);
        o[nt] = __builtin_amdgcn_mfma_f32_16x16x32_bf16(ap, bv, o[nt], 0, 0, 0);
      }
    }
    __syncthreads();   // done with sK/sV/sP before next staging
  }

  // epilogue: O/l -> Y (B,T,4096)
#pragma unroll
  for (int r = 0; r < 4; ++r){
    int t = q0 + wave * 16 + quad * 4 + r;
    float inv = 1.0f / li[r];
    size_t ybase = ((size_t)(b * 2048 + t)) * 4096 + h * 128;
#pragma unroll
    for (int nt = 0; nt < 8; ++nt)
      Y[ybase + nt * 16 + lrow] = f2b(o[nt][r] * inv);
  }
}

// ---------------------------------------------------------------- launch
extern "C" void kernel_launch(void* const* d_in, const int* in_sizes, int n_in,
                              void* d_out, int out_size, void* d_ws, size_t ws_size,
                              hipStream_t stream)
{
  (void)in_sizes; (void)n_in; (void)out_size; (void)ws_size;
  const float* x    = (const float*)d_in[0];   // (2,2048,4096)
  const float* fc   = (const float*)d_in[1];   // (2048,64)
  const float* fs   = (const float*)d_in[2];   // (2048,64)
  const float* wqkv = (const float*)d_in[3];   // (6144,4096)
  const float* wo   = (const float*)d_in[4];   // (4096,4096)
  float* out = (float*)d_out;                  // (2,2048,4096) f32

  char* ws = (char*)d_ws;
  u16t* xb    = (u16t*)(ws);                    // 32 MiB (reused as yb after gemm1)
  u16t* wqkvb = (u16t*)(ws + 33554432);         // 48 MiB
  u16t* wob   = (u16t*)(ws + 83886080);         // 32 MiB
  u16t* qkvb  = (u16t*)(ws + 117440512);        // 48 MiB
  u16t* qr    = (u16t*)(ws + 167772160);        // 32 MiB
  u16t* kr    = (u16t*)(ws + 201326592);        //  8 MiB
  u16t* vt    = (u16t*)(ws + 209715200);        //  8 MiB  (total 208 MiB)
  u16t* yb    = xb;                             // alias: x dead after gemm1

  cvt_f32_bf16<<<4096, 256, 0, stream>>>(x,    xb,    16777216 / 4);
  cvt_f32_bf16<<<4096, 256, 0, stream>>>(wqkv, wqkvb, 25165824 / 4);
  cvt_f32_bf16<<<4096, 256, 0, stream>>>(wo,   wob,   16777216 / 4);
  gemm_bt<1><<<dim3(48, 32), 256, 0, stream>>>(xb, wqkvb, qkvb, 4096, 6144, 4096);
  rope_qk<<<4096, 256, 0, stream>>>(qkvb, fc, fs, qr, kr);
  vtrans<<<512, 256, 0, stream>>>(qkvb, vt);
  attn_fwd<<<dim3(32, 64), 256, 0, stream>>>(qr, kr, vt, yb);
  gemm_bt<0><<<dim3(32, 32), 256, 0, stream>>>(yb, wob, out, 4096, 4096, 4096);
}

// Round 2
// 938.320 us; speedup vs baseline: 1.4148x; 1.4148x over previous
//
#include <hip/hip_runtime.h>

typedef unsigned short u16t;
typedef unsigned int   u32t;
typedef __attribute__((ext_vector_type(8))) __bf16          bf16x8;
typedef __attribute__((ext_vector_type(8))) unsigned short  u16x8;
typedef __attribute__((ext_vector_type(4))) unsigned short  u16x4;
typedef __attribute__((ext_vector_type(4))) float           floatx4;

// f32 -> bf16 round-to-nearest-even (no NaN inputs in this problem)
__device__ __forceinline__ u16t f2b(float f){
  u32t u = __builtin_bit_cast(u32t, f);
  u += 0x7fffu + ((u >> 16) & 1u);
  return (u16t)(u >> 16);
}
__device__ __forceinline__ float b2f(u16t h){
  return __builtin_bit_cast(float, (u32t)h << 16);
}
// async global->LDS, 16B per lane. lds ptr must be wave-uniform (HW adds lane*16).
__device__ __forceinline__ void async16(const void* g, void* l){
  __builtin_amdgcn_global_load_lds((__attribute__((address_space(1))) void*)g,
                                   (__attribute__((address_space(3))) void*)l, 16, 0, 0);
}
__device__ __forceinline__ bf16x8 ldfrag(const u16t* p){
  return __builtin_bit_cast(bf16x8, *(const u16x8*)p);
}

// ---------------------------------------------------------------- cvt f32->bf16
__global__ __launch_bounds__(256)
void cvt_f32_bf16(const float* __restrict__ in, u16t* __restrict__ out, int n4){
  typedef __attribute__((ext_vector_type(4))) float f32x4;
  const f32x4* in4 = (const f32x4*)in;
  int stride = gridDim.x * blockDim.x;
  for (int i = blockIdx.x * blockDim.x + threadIdx.x; i < n4; i += stride){
    f32x4 v = in4[i];
    u16x4 o; o[0]=f2b(v[0]); o[1]=f2b(v[1]); o[2]=f2b(v[2]); o[3]=f2b(v[3]);
    *(u16x4*)(out + (size_t)i * 4) = o;
  }
}

// ---------------------------------------------------------------- GEMM C = A * B^T
// m97 structure: 128x128 tile, BK=32, 4 waves, 4x4 16x16x32 MFMA per wave.
// (stride-32 u16 rows = 64B -> fragment reads already hit the 8-group spread; no conflict fix needed)
template<int OUT_BF16>
__global__ __launch_bounds__(256)
void gemm_bt(const u16t* __restrict__ A, const u16t* __restrict__ B,
             void* __restrict__ Cv, int M, int N, int K)
{
  __shared__ u16t sA[128 * 32];
  __shared__ u16t sB[128 * 32];
  const int tid  = threadIdx.x;
  const int wave = tid >> 6, lane = tid & 63;
  const int lrow = lane & 15, quad = lane >> 4;
  const int m0 = blockIdx.y * 128, n0 = blockIdx.x * 128;
  const int wm = (wave >> 1) * 64, wn = (wave & 1) * 64;

  floatx4 acc[4][4] = {};

  const int byte0 = wave * 1024 + lane * 16;
  const int row0  = byte0 >> 6;
  const int kel0  = (byte0 & 63) >> 1;
  const int row1  = row0 + 64;

  char* lA0 = (char*)sA + wave * 1024;
  char* lA1 = (char*)sA + 4096 + wave * 1024;
  char* lB0 = (char*)sB + wave * 1024;
  char* lB1 = (char*)sB + 4096 + wave * 1024;

  const u16t* gA0 = A + (size_t)(m0 + row0) * K + kel0;
  const u16t* gA1 = A + (size_t)(m0 + row1) * K + kel0;
  const u16t* gB0 = B + (size_t)(n0 + row0) * K + kel0;
  const u16t* gB1 = B + (size_t)(n0 + row1) * K + kel0;

  for (int k0 = 0; k0 < K; k0 += 32){
    async16(gA0 + k0, lA0);
    async16(gA1 + k0, lA1);
    async16(gB0 + k0, lB0);
    async16(gB1 + k0, lB1);
    __syncthreads();
    bf16x8 a[4], b[4];
#pragma unroll
    for (int i = 0; i < 4; ++i) a[i] = ldfrag(&sA[(wm + i * 16 + lrow) * 32 + quad * 8]);
#pragma unroll
    for (int j = 0; j < 4; ++j) b[j] = ldfrag(&sB[(wn + j * 16 + lrow) * 32 + quad * 8]);
#pragma unroll
    for (int i = 0; i < 4; ++i)
#pragma unroll
      for (int j = 0; j < 4; ++j)
        acc[i][j] = __builtin_amdgcn_mfma_f32_16x16x32_bf16(a[i], b[j], acc[i][j], 0, 0, 0);
    __syncthreads();
  }

#pragma unroll
  for (int i = 0; i < 4; ++i)
#pragma unroll
    for (int j = 0; j < 4; ++j)
#pragma unroll
      for (int r = 0; r < 4; ++r){
        int row = m0 + wm + i * 16 + quad * 4 + r;
        int col = n0 + wn + j * 16 + lrow;
        float v = acc[i][j][r];
        if (OUT_BF16) ((u16t*)Cv)[(size_t)row * N + col] = f2b(v);
        else          ((float*)Cv)[(size_t)row * N + col] = v;
      }
}

// ---------------------------------------------------------------- RoPE + layout
__global__ __launch_bounds__(256)
void rope_qk(const u16t* __restrict__ qkvb, const float* __restrict__ cosp,
             const float* __restrict__ sinp, u16t* __restrict__ qr, u16t* __restrict__ kr)
{
  const int row = blockIdx.x;            // b*2048 + t
  const int b = row >> 11, t = row & 2047;
  const u16t* src = qkvb + (size_t)row * 6144;
  for (int p = threadIdx.x; p < 2560; p += 256){
    u32t both = *(const u32t*)(src + 2 * p);
    float t0 = b2f((u16t)(both & 0xffff));
    float t1 = b2f((u16t)(both >> 16));
    int j = p & 63;
    float c = cosp[t * 64 + j], s = sinp[t * 64 + j];
    float o0 = t0 * c - t1 * s;
    float o1 = t0 * s + t1 * c;
    u32t packed = (u32t)f2b(o0) | ((u32t)f2b(o1) << 16);
    if (p < 2048){
      int h = p >> 6;
      *(u32t*)(qr + (((size_t)(b * 32 + h) * 2048 + t) * 128 + 2 * j)) = packed;
    } else {
      int kh = (p - 2048) >> 6;
      *(u32t*)(kr + (((size_t)(b * 8 + kh) * 2048 + t) * 128 + 2 * j)) = packed;
    }
  }
}

// ---------------------------------------------------------------- V transpose
__global__ __launch_bounds__(256)
void vtrans(const u16t* __restrict__ qkvb, u16t* __restrict__ vt)
{
  __shared__ u16t sV[64 * 128];
  const int tid = threadIdx.x;
  const int blk = blockIdx.x;                 // (b, kvh, tile)
  const int tile = blk & 31, kvh = (blk >> 5) & 7, b = blk >> 8;
  const int t0 = tile * 64;
  const size_t srcbase = (size_t)(b * 2048 + t0) * 6144 + 5120 + kvh * 128;
#pragma unroll
  for (int it = 0; it < 4; ++it){
    int task = it * 256 + tid;
    int rrow = task >> 4, cb = task & 15;
    *(u16x8*)&sV[rrow * 128 + cb * 8] =
        *(const u16x8*)(qkvb + srcbase + (size_t)rrow * 6144 + cb * 8);
  }
  __syncthreads();
  const size_t dstbase = (size_t)((b * 8 + kvh) * 128) * 2048 + t0;
#pragma unroll
  for (int it = 0; it < 4; ++it){
    int task = it * 256 + tid;
    int tc = task & 7, d = task >> 3;
    u16x8 v;
#pragma unroll
    for (int j = 0; j < 8; ++j) v[j] = sV[(tc * 8 + j) * 128 + d];
    *(u16x8*)(vt + dstbase + (size_t)d * 2048 + tc * 8) = v;
  }
}

// ---------------------------------------------------------------- flash attention v2
// Q (B,32,T,128), K (B,8,T,128), Vt (B,8,128,T) bf16 -> Y (B,T,32*128) bf16.
// LDS in chunk-transposed (d-major) layout: 16B chunk index = dc*64+row so the
// b128 fragment read spreads lrow across the 8 bank-groups (conflict-free).
// sP aliases sK (K dead after S); 48 KB LDS -> 3 blocks/CU.
__global__ __launch_bounds__(256)
void attn_fwd(const u16t* __restrict__ Qg, const u16t* __restrict__ Kg,
              const u16t* __restrict__ Vt, u16t* __restrict__ Y)
{
  __shared__ u16t smem[24576];         // 48 KB
  u16t* sQ = smem;                     // [dc:16][row:64] 16B chunks
  u16t* sK = smem + 8192;              // [dc:16][row:64]
  u16t* sV = smem + 16384;             // [kvc:8][d:128]
  u16t* sP = sK;                       // [q:64][kv], stride 72 u16 (aliases sK)

  const int tid  = threadIdx.x;
  const int wave = tid >> 6, lane = tid & 63;
  const int lrow = lane & 15, quad = lane >> 4;
  const int qt = 31 - (int)blockIdx.y;     // longest blocks dispatch first
  const int q0 = qt * 64;
  const int bh = blockIdx.x;
  const int b = bh >> 5, h = bh & 31, kvh = h >> 2;
  const float qscale = 0.088388347648318447f * 1.4426950408889634f; // 1/sqrt(128)*log2(e)

  // stage Q tile, d-major: round r, wave w holds dchunk dc=r*4+w, row=lane
  const size_t qbase = ((size_t)bh * 2048 + q0) * 128;
#pragma unroll
  for (int r = 0; r < 4; ++r){
    const int dc = r * 4 + wave;
    async16(Qg + qbase + (size_t)lane * 128 + dc * 8, (char*)sQ + dc * 1024);
  }

  float mi[4] = {-1e30f, -1e30f, -1e30f, -1e30f};
  float li[4] = {0.f, 0.f, 0.f, 0.f};
  floatx4 o[8] = {};
  const size_t kbase = ((size_t)(b * 8 + kvh) * 2048) * 128;
  const size_t vbase = ((size_t)(b * 8 + kvh) * 128) * 2048;
  const int qrow_base = q0 + wave * 16 + quad * 4;
  const int ktiles = qt + 1;

  for (int kt = 0; kt < ktiles; ++kt){
    const int k0 = kt * 64;
#pragma unroll
    for (int r = 0; r < 4; ++r){
      const int dc = r * 4 + wave;
      async16(Kg + kbase + (size_t)(k0 + lane) * 128 + dc * 8, (char*)sK + dc * 1024);
    }
#pragma unroll
    for (int r = 0; r < 4; ++r){
      const int kvc = r * 2 + (wave >> 1);
      const int dd  = (wave & 1) * 64 + lane;
      async16(Vt + vbase + (size_t)dd * 2048 + k0 + kvc * 8,
              (char*)sV + kvc * 2048 + (wave & 1) * 1024);
    }
    __syncthreads();   // K/V (and first-iter Q) tiles ready

    // S = Q K^T
    floatx4 s[4] = {};
#pragma unroll
    for (int kk = 0; kk < 4; ++kk){
      bf16x8 aq = ldfrag(&sQ[((kk * 4 + quad) * 64 + wave * 16 + lrow) * 8]);
#pragma unroll
      for (int nt = 0; nt < 4; ++nt){
        bf16x8 bk = ldfrag(&sK[((kk * 4 + quad) * 64 + nt * 16 + lrow) * 8]);
        s[nt] = __builtin_amdgcn_mfma_f32_16x16x32_bf16(aq, bk, s[nt], 0, 0, 0);
      }
    }
    __syncthreads();   // all sK reads complete before sP (alias) is written

    // scale (+ causal mask on the diagonal tile)
    float tt[4][4];
#pragma unroll
    for (int nt = 0; nt < 4; ++nt)
#pragma unroll
      for (int r = 0; r < 4; ++r)
        tt[nt][r] = s[nt][r] * qscale;
    if (kt == ktiles - 1){
#pragma unroll
      for (int nt = 0; nt < 4; ++nt){
        int kc = k0 + nt * 16 + lrow;
#pragma unroll
        for (int r = 0; r < 4; ++r)
          if (kc > qrow_base + r) tt[nt][r] = -1e30f;
      }
    }

    // row max over 64 cols (cols live across lrow lanes)
    float rmax[4];
#pragma unroll
    for (int r = 0; r < 4; ++r)
      rmax[r] = fmaxf(fmaxf(tt[0][r], tt[1][r]), fmaxf(tt[2][r], tt[3][r]));
#pragma unroll
    for (int off = 1; off < 16; off <<= 1){
#pragma unroll
      for (int r = 0; r < 4; ++r)
        rmax[r] = fmaxf(rmax[r], __shfl_xor(rmax[r], off, 64));
    }
    float alpha[4];
#pragma unroll
    for (int r = 0; r < 4; ++r){
      float mn = fmaxf(mi[r], rmax[r]);
      alpha[r] = __builtin_amdgcn_exp2f(mi[r] - mn);
      mi[r] = mn;
    }
    float lsum[4] = {0.f, 0.f, 0.f, 0.f};
#pragma unroll
    for (int nt = 0; nt < 4; ++nt)
#pragma unroll
      for (int r = 0; r < 4; ++r){
        float e = __builtin_amdgcn_exp2f(tt[nt][r] - mi[r]);
        lsum[r] += e;
        sP[(wave * 16 + quad * 4 + r) * 72 + nt * 16 + lrow] = f2b(e);
      }
#pragma unroll
    for (int off = 1; off < 16; off <<= 1){
#pragma unroll
      for (int r = 0; r < 4; ++r)
        lsum[r] += __shfl_xor(lsum[r], off, 64);
    }
#pragma unroll
    for (int r = 0; r < 4; ++r) li[r] = li[r] * alpha[r] + lsum[r];
#pragma unroll
    for (int nt = 0; nt < 8; ++nt){
      o[nt][0] *= alpha[0]; o[nt][1] *= alpha[1];
      o[nt][2] *= alpha[2]; o[nt][3] *= alpha[3];
    }
    // no barrier needed: each wave reads back only its own sP rows (same-wave
    // LDS RAW is ordered by the DS pipe / lgkmcnt)

    // O += P V
#pragma unroll
    for (int kk = 0; kk < 2; ++kk){
      bf16x8 ap = ldfrag(&sP[(wave * 16 + lrow) * 72 + kk * 32 + quad * 8]);
#pragma unroll
      for (int nt = 0; nt < 8; ++nt){
        bf16x8 bv = ldfrag(&sV[((kk * 4 + quad) * 128 + nt * 16 + lrow) * 8]);
        o[nt] = __builtin_amdgcn_mfma_f32_16x16x32_bf16(ap, bv, o[nt], 0, 0, 0);
      }
    }
    __syncthreads();   // sP/sV reads done before next-iter staging
  }

  // epilogue: O/l -> Y (B,T,4096)
#pragma unroll
  for (int r = 0; r < 4; ++r){
    int t = q0 + wave * 16 + quad * 4 + r;
    float inv = 1.0f / li[r];
    size_t ybase = ((size_t)(b * 2048 + t)) * 4096 + h * 128;
#pragma unroll
    for (int nt = 0; nt < 8; ++nt)
      Y[ybase + nt * 16 + lrow] = f2b(o[nt][r] * inv);
  }
}

// ---------------------------------------------------------------- launch
extern "C" void kernel_launch(void* const* d_in, const int* in_sizes, int n_in,
                              void* d_out, int out_size, void* d_ws, size_t ws_size,
                              hipStream_t stream)
{
  (void)in_sizes; (void)n_in; (void)out_size; (void)ws_size;
  const float* x    = (const float*)d_in[0];   // (2,2048,4096)
  const float* fc   = (const float*)d_in[1];   // (2048,64)
  const float* fs   = (const float*)d_in[2];   // (2048,64)
  const float* wqkv = (const float*)d_in[3];   // (6144,4096)
  const float* wo   = (const float*)d_in[4];   // (4096,4096)
  float* out = (float*)d_out;                  // (2,2048,4096) f32

  char* ws = (char*)d_ws;
  u16t* xb    = (u16t*)(ws);                    // 32 MiB (reused as yb after gemm1)
  u16t* wqkvb = (u16t*)(ws + 33554432);         // 48 MiB
  u16t* wob   = (u16t*)(ws + 83886080);         // 32 MiB
  u16t* qkvb  = (u16t*)(ws + 117440512);        // 48 MiB
  u16t* qr    = (u16t*)(ws + 167772160);        // 32 MiB
  u16t* kr    = (u16t*)(ws + 201326592);        //  8 MiB
  u16t* vt    = (u16t*)(ws + 209715200);        //  8 MiB  (total 208 MiB)
  u16t* yb    = xb;                             // alias: x dead after gemm1

  cvt_f32_bf16<<<4096, 256, 0, stream>>>(x,    xb,    16777216 / 4);
  cvt_f32_bf16<<<4096, 256, 0, stream>>>(wqkv, wqkvb, 25165824 / 4);
  cvt_f32_bf16<<<4096, 256, 0, stream>>>(wo,   wob,   16777216 / 4);
  gemm_bt<1><<<dim3(48, 32), 256, 0, stream>>>(xb, wqkvb, qkvb, 4096, 6144, 4096);
  rope_qk<<<4096, 256, 0, stream>>>(qkvb, fc, fs, qr, kr);
  vtrans<<<512, 256, 0, stream>>>(qkvb, vt);
  attn_fwd<<<dim3(64, 32), 256, 0, stream>>>(qr, kr, vt, yb);
  gemm_bt<0><<<dim3(32, 32), 256, 0, stream>>>(yb, wob, out, 4096, 4096, 4096);
}